// Round 1
// 926.463 us; speedup vs baseline: 1.0436x; 1.0436x over previous
//
#include <hip/hip_runtime.h>
#include <math.h>

#define INC   128
#define HID   32
#define NSEG  16

// ---- non-temporal 16B load/store (streaming, no L2/L3 pollution) ----------
typedef float f4v __attribute__((ext_vector_type(4)));

__device__ __forceinline__ float4 ntload4(const float4* p) {
    f4v v = __builtin_nontemporal_load((const f4v*)p);
    return make_float4(v.x, v.y, v.z, v.w);
}
__device__ __forceinline__ void ntstore4(float4* p, float4 f) {
    f4v v = {f.x, f.y, f.z, f.w};
    __builtin_nontemporal_store(v, (f4v*)p);
}

// Order-preserving float <-> uint mapping so unsigned atomicMax works for
// float max (handles negatives; encode(any real) >= 0x007FFFFF > 0, so a
// zero-initialized accumulator is a valid identity).
__device__ __forceinline__ unsigned f2ord(float f) {
    unsigned u = __float_as_uint(f);
    return (u & 0x80000000u) ? ~u : (u | 0x80000000u);
}
__device__ __forceinline__ float ord2f(unsigned u) {
    return (u & 0x80000000u) ? __uint_as_float(u & 0x7fffffffu)
                             : __uint_as_float(~u);
}

__device__ __forceinline__ void flush_lds8(int seg, int c8,
                                           const float4& s0, const float4& s1,
                                           const float4& m0, const float4& m1,
                                           float cnt, float* s_sum,
                                           unsigned* s_max, float* s_cnt) {
    int base = seg * INC + c8 * 8;
    atomicAdd(&s_sum[base + 0], s0.x);
    atomicAdd(&s_sum[base + 1], s0.y);
    atomicAdd(&s_sum[base + 2], s0.z);
    atomicAdd(&s_sum[base + 3], s0.w);
    atomicAdd(&s_sum[base + 4], s1.x);
    atomicAdd(&s_sum[base + 5], s1.y);
    atomicAdd(&s_sum[base + 6], s1.z);
    atomicAdd(&s_sum[base + 7], s1.w);
    atomicMax(&s_max[base + 0], f2ord(m0.x));
    atomicMax(&s_max[base + 1], f2ord(m0.y));
    atomicMax(&s_max[base + 2], f2ord(m0.z));
    atomicMax(&s_max[base + 3], f2ord(m0.w));
    atomicMax(&s_max[base + 4], f2ord(m1.x));
    atomicMax(&s_max[base + 5], f2ord(m1.y));
    atomicMax(&s_max[base + 6], f2ord(m1.z));
    atomicMax(&s_max[base + 7], f2ord(m1.w));
    if (c8 == 0) atomicAdd(&s_cnt[seg], cnt);
}

// ---------------- Kernel 1: segment sum / max / count -----------------------
// batch_idx is SORTED: each block's contiguous row chunk spans ~1-2 segments,
// so per-thread register accumulation flushes to LDS ~once, and the block
// does ~128*nseg global atomics total.
// Widened vs prev round: 8 floats/thread/row (2x dwordx4) -> 2 KB in flight
// per wave-iteration instead of 1 KB, half the bidx loop trips.
__global__ __launch_bounds__(256) void seg_reduce_kernel(
    const float4* __restrict__ feats4, const int* __restrict__ bidx,
    float* __restrict__ gsum, unsigned* __restrict__ gmax,
    float* __restrict__ gcnt, int nrows)
{
    __shared__ float    s_sum[NSEG * INC];
    __shared__ unsigned s_max[NSEG * INC];
    __shared__ float    s_cnt[NSEG];

    const int tid   = threadIdx.x;
    const int chunk = (nrows + gridDim.x - 1) / gridDim.x;
    const int start = blockIdx.x * chunk;
    if (start >= nrows) return;                    // uniform per block
    const int end = min(start + chunk, nrows);

    for (int i = tid; i < NSEG * INC; i += 256) { s_sum[i] = 0.f; s_max[i] = 0u; }
    if (tid < NSEG) s_cnt[tid] = 0.f;
    __syncthreads();

    const int c8   = tid & 15;   // which 8-float group of the row (0..15)
    const int slot = tid >> 4;   // row slot (0..15): 16 rows per iteration
    int    cur = -1;
    float4 s0 = make_float4(0.f, 0.f, 0.f, 0.f), s1 = s0;
    float4 m0 = s0, m1 = s0;
    float  cnt = 0.f;

    for (int r = start + slot; r < end; r += 16) {
        int           seg  = bidx[r];
        const float4* rowp = feats4 + (size_t)r * (INC / 4) + c8 * 2;
        float4        f0   = ntload4(rowp);
        float4        f1   = ntload4(rowp + 1);
        if (seg != cur) {
            if (cur >= 0) flush_lds8(cur, c8, s0, s1, m0, m1, cnt, s_sum, s_max, s_cnt);
            cur = seg; s0 = f0; s1 = f1; m0 = f0; m1 = f1; cnt = 1.f;
        } else {
            s0.x += f0.x; s0.y += f0.y; s0.z += f0.z; s0.w += f0.w;
            s1.x += f1.x; s1.y += f1.y; s1.z += f1.z; s1.w += f1.w;
            m0.x = fmaxf(m0.x, f0.x); m0.y = fmaxf(m0.y, f0.y);
            m0.z = fmaxf(m0.z, f0.z); m0.w = fmaxf(m0.w, f0.w);
            m1.x = fmaxf(m1.x, f1.x); m1.y = fmaxf(m1.y, f1.y);
            m1.z = fmaxf(m1.z, f1.z); m1.w = fmaxf(m1.w, f1.w);
            cnt += 1.f;
        }
    }
    if (cur >= 0) flush_lds8(cur, c8, s0, s1, m0, m1, cnt, s_sum, s_max, s_cnt);
    __syncthreads();

    // Global flush: only segments present in [start, end) (sorted => a range).
    // 256 threads = 2 segments in flight per pass.
    const int sf  = bidx[start];
    const int sl  = bidx[end - 1];
    const int col = tid & (INC - 1);
    for (int s = sf + (tid >> 7); s <= sl; s += 2) {
        atomicAdd(&gsum[s * INC + col], s_sum[s * INC + col]);
        atomicMax(&gmax[s * INC + col], s_max[s * INC + col]);
        if (col == 0) atomicAdd(&gcnt[s], s_cnt[s]);
    }
}

// ---------------- Kernel 2: tiny MLPs + sigmoid -> gate[16][128] ------------
// gate = sigmoid(mlp(mean) + mlp(max)); note b2 appears TWICE.
// Weights staged in LDS with coalesced loads (single-block kernel; avoids
// serialized cold-miss reads of W1/W2 in the MAC loops).
__global__ __launch_bounds__(256) void mlp_kernel(
    const float* __restrict__ gsum, const unsigned* __restrict__ gmax,
    const float* __restrict__ gcnt,
    const float* __restrict__ W1, const float* __restrict__ b1,
    const float* __restrict__ W2, const float* __restrict__ b2,
    float* __restrict__ gate)
{
    __shared__ float s_mean[NSEG * INC];
    __shared__ float s_max [NSEG * INC];
    __shared__ float s_h   [NSEG * HID];   // relu(h_mean) + relu(h_max)
    __shared__ float s_W1  [INC * HID];    // 16 KB
    __shared__ float s_W2  [HID * INC];    // 16 KB
    __shared__ float s_b1  [HID];
    __shared__ float s_b2  [INC];
    const int tid = threadIdx.x;

    for (int i = tid; i < INC * HID; i += 256) { s_W1[i] = W1[i]; s_W2[i] = W2[i]; }
    if (tid < HID) s_b1[tid] = b1[tid];
    if (tid < INC) s_b2[tid] = b2[tid];

    for (int i = tid; i < NSEG * INC; i += 256) {
        int   s = i >> 7;  // /INC
        float c = gcnt[s];
        s_mean[i] = gsum[i] / fmaxf(c, 1.f);
        s_max[i]  = (c > 0.f) ? ord2f(gmax[i]) : 0.f;  // empty-segment guard
    }
    __syncthreads();

    for (int i = tid; i < NSEG * HID; i += 256) {
        int s = i / HID, h = i % HID;
        float am = s_b1[h], ax = s_b1[h];
        for (int c = 0; c < INC; c++) {
            float w = s_W1[c * HID + h];             // W1 is [INC][HID]
            am += s_mean[s * INC + c] * w;
            ax += s_max [s * INC + c] * w;
        }
        s_h[i] = fmaxf(am, 0.f) + fmaxf(ax, 0.f);
    }
    __syncthreads();

    for (int i = tid; i < NSEG * INC; i += 256) {
        int s = i >> 7, c = i & (INC - 1);
        float a = 2.f * s_b2[c];                     // b2 added in BOTH mlps
        for (int h = 0; h < HID; h++) a += s_h[s * HID + h] * s_W2[h * INC + c];
        gate[i] = 1.f / (1.f + expf(-a));
    }
}

// ---------------- Kernel 3: out = feats * gate[batch_idx] -------------------
__global__ __launch_bounds__(256) void apply_kernel(
    const float4* __restrict__ feats4, const int* __restrict__ bidx,
    const float4* __restrict__ gate4, float4* __restrict__ out4, int nrows)
{
    __shared__ float4 s_gate[NSEG * (INC / 4)];      // 8 KB, LDS-guaranteed hit
    for (int i = threadIdx.x; i < NSEG * (INC / 4); i += blockDim.x)
        s_gate[i] = gate4[i];
    __syncthreads();

    const int total = nrows * (INC / 4);
    for (int idx = blockIdx.x * blockDim.x + threadIdx.x; idx < total;
         idx += gridDim.x * blockDim.x) {
        int    r   = idx >> 5;                        // / (INC/4)
        int    c4  = idx & 31;
        int    seg = bidx[r];
        float4 f   = ntload4(&feats4[idx]);
        float4 g   = s_gate[seg * (INC / 4) + c4];
        ntstore4(&out4[idx],
                 make_float4(f.x * g.x, f.y * g.y, f.z * g.z, f.w * g.w));
    }
}

extern "C" void kernel_launch(void* const* d_in, const int* in_sizes, int n_in,
                              void* d_out, int out_size, void* d_ws, size_t ws_size,
                              hipStream_t stream) {
    const float* feats = (const float*)d_in[0];
    const int*   bidx  = (const int*)d_in[1];
    const float* W1    = (const float*)d_in[2];
    const float* b1    = (const float*)d_in[3];
    const float* W2    = (const float*)d_in[4];
    const float* b2    = (const float*)d_in[5];
    float*       out   = (float*)d_out;
    const int nrows    = in_sizes[1];                 // N from batch_idx

    // Workspace layout (ws is re-poisoned to 0xAA each call -> must memset):
    //   [0,      8192)  gsum  float[16*128]
    //   [8192,  16384)  gmax  uint [16*128]  (order-mapped)
    //   [16384, 16448)  gcnt  float[16]
    //   [16448, 24640)  gate  float[16*128]  (16B-aligned for float4)
    char*     ws   = (char*)d_ws;
    float*    gsum = (float*)(ws);
    unsigned* gmax = (unsigned*)(ws + 8192);
    float*    gcnt = (float*)(ws + 16384);
    float*    gate = (float*)(ws + 16448);

    hipMemsetAsync(d_ws, 0, 16448, stream);           // zero accumulators only

    seg_reduce_kernel<<<2048, 256, 0, stream>>>(
        (const float4*)feats, bidx, gsum, gmax, gcnt, nrows);
    mlp_kernel<<<1, 256, 0, stream>>>(gsum, gmax, gcnt, W1, b1, W2, b2, gate);
    apply_kernel<<<8192, 256, 0, stream>>>(
        (const float4*)feats, bidx, (const float4*)gate, (float4*)out, nrows);
}